// Round 1
// baseline (37289.709 us; speedup 1.0000x reference)
//
#include <hip/hip_runtime.h>

// RateRNN with Dale's law — MI355X (gfx950)
//
// Structure:
//  k_input : I_exc = relu(x @ W_ih^T)  -> written into d_out's hidden slots
//            (scan reads ie row t, then overwrites the same row with h_t)
//  k_scan  : 2048 sequential steps; 32 blocks (1 per batch), W_hh held
//            entirely in VGPRs (1024 thr x 64 float4 = 1 MB / block).
//            No fp32 MFMA on CDNA4 -> VALU issue floor = 2048 cyc/step/CU.
//  k_logits: out = softmax(sigmoid(hidden[:, :, :EXC]) @ W_ho^T)

#define B_N 32
#define S_N 2048
#define IN_N 64
#define OUT_N 64
#define HID_N 512
#define EXC_N 410
#define PAIRS (B_N * S_N)

__device__ __forceinline__ float sigf(float v) {
  return 1.0f / (1.0f + __expf(-v));
}

// ---------------------------------------------------------------- kernel 1
// 512 thr = 8 waves; each wave handles 16 (b,t) pairs, x staged in LDS,
// W_ih rows streamed from global (L1-resident per 64-row chunk).
__global__ __launch_bounds__(512) void k_input(
    const float* __restrict__ x, const float* __restrict__ W_ih,
    float* __restrict__ hid)
{
  __shared__ float4 xl[8][16][16];   // [wave][pair][i4] = 32 KB
  const int wave = threadIdx.x >> 6, lane = threadIdx.x & 63;
  const int base = (blockIdx.x * 8 + wave) * 16;   // first pair id of wave

  const float4* xg = (const float4*)(x + (size_t)base * IN_N);
  #pragma unroll
  for (int it = 0; it < 4; ++it) {
    int k = it * 64 + lane;          // float4 index 0..255 (coalesced)
    xl[wave][k >> 4][k & 15] = xg[k];
  }
  __syncthreads();

  #pragma unroll 1
  for (int c = 0; c < 7; ++c) {
    int e = c * 64 + lane;
    bool ok = (e < EXC_N);
    float acc[16];
    #pragma unroll
    for (int p = 0; p < 16; ++p) acc[p] = 0.f;
    const float4* wrow = (const float4*)(W_ih + (size_t)(ok ? e : 0) * IN_N);
    #pragma unroll
    for (int i4 = 0; i4 < 16; ++i4) {
      float4 w4 = wrow[i4];
      #pragma unroll
      for (int p = 0; p < 16; ++p) {
        float4 x4 = xl[wave][p][i4];     // LDS broadcast (free)
        acc[p] = fmaf(w4.x, x4.x, acc[p]);
        acc[p] = fmaf(w4.y, x4.y, acc[p]);
        acc[p] = fmaf(w4.z, x4.z, acc[p]);
        acc[p] = fmaf(w4.w, x4.w, acc[p]);
      }
    }
    if (ok) {
      #pragma unroll
      for (int p = 0; p < 16; ++p)
        hid[(size_t)(base + p) * HID_N + e] = fmaxf(acc[p], 0.f);
    }
  }
}

// ---------------------------------------------------------------- kernel 2
// One block per batch element. thread t: output row j = t>>1, K-half = t&1,
// holds W_hh[j][half*256 .. +256) in 64 float4 VGPRs (256 regs).
// Per step: sigmoid -> barrier -> (prefetch next streams) dot ->
// pair-reduce via shfl_xor -> update h in LDS -> barrier.
// Previous h row stored coalesced by threads 0..511 at next phase 1.
__global__ __launch_bounds__(1024, 4) void k_scan(
    const float* __restrict__ h0, const float* __restrict__ W_hh,
    const float* __restrict__ noise, float* __restrict__ hid)
{
  __shared__ float  h_l[HID_N];
  __shared__ float4 s_l4[HID_N / 4];
  __shared__ float  ie_l[EXC_N];
  __shared__ float  nz_l[HID_N];
  __shared__ float  osc_l[S_N];
  float* s_l = (float*)s_l4;

  const int t = threadIdx.x;
  const int b = blockIdx.x;
  const int j = t >> 1;
  const int half = t & 1;

  // W rows -> registers (one-time, ~1 MB/block; L3-cached after block 0)
  float4 w[64];
  {
    const float4* wr = (const float4*)(W_hh + (size_t)j * HID_N + half * 256);
    #pragma unroll
    for (int u = 0; u < 64; ++u) w[u] = wr[u];
  }

  if (t < HID_N) h_l[t] = h0[(size_t)b * HID_N + t];
  // osc[t] = sin(((16*pi)*t)*DT) + 1   (f32 rounding order matches XLA)
  #pragma unroll
  for (int q = 0; q < S_N / 1024; ++q) {
    int st = q * 1024 + t;
    osc_l[st] = sinf((50.26548245743669f * (float)st) * 0.01f) + 1.0f;
  }

  float* hb = hid + (size_t)b * S_N * HID_N;

  // prefetch step-0 streams into registers
  float nz_r = 0.f, ie_r = 0.f;
  if (t < HID_N) {
    nz_r = noise[((size_t)b) * HID_N + t];          // step 0
  } else {
    int u = t - HID_N;
    if (u < EXC_N) ie_r = hb[u];                    // ie row 0
  }
  __syncthreads();

  #pragma unroll 1
  for (int step = 0; step < S_N; ++step) {
    float* row = hb + (size_t)step * HID_N;
    // ---- phase 1: publish streams to LDS, sigmoid, store previous h ----
    if (t < HID_N) {
      nz_l[t] = nz_r;
      float hv = h_l[t];
      if (step > 0) (row - HID_N)[t] = hv;          // coalesced store
      s_l[t] = 1.0f / (1.0f + __expf(-hv));
    } else {
      int u = t - HID_N;
      if (u < EXC_N) ie_l[u] = ie_r;
    }
    __syncthreads();

    // ---- prefetch next-step streams (latency hides under the FMA block)
    int ps = (step + 1 < S_N) ? step + 1 : S_N - 1;
    if (t < HID_N) {
      nz_r = noise[((size_t)ps * B_N + b) * HID_N + t];
    } else {
      int u = t - HID_N;
      if (u < EXC_N) ie_r = hb[(size_t)ps * HID_N + u];
    }

    // ---- dot: 256 FMAs/thread, s read as 2-address LDS broadcast ----
    const float4* sv = s_l4 + half * 64;
    float p0 = 0.f, p1 = 0.f;
    #pragma unroll
    for (int u = 0; u < 64; ++u) {
      float4 s4 = sv[u];
      p0 = fmaf(w[u].x, s4.x, p0);
      p1 = fmaf(w[u].y, s4.y, p1);
      p0 = fmaf(w[u].z, s4.z, p0);
      p1 = fmaf(w[u].w, s4.w, p1);
    }
    float dot = p0 + p1;
    dot += __shfl_xor(dot, 1);   // both lanes of the pair get the full sum

    // ---- update ----
    if (half == 0) {
      float r = fmaxf(dot, 0.f);                       // relu
      float I = (j < EXC_N) ? (r + ie_l[j])            // sign=+1, + ie
                            : (osc_l[step] - r);       // sign=-1, + osc
      float hn = fmaf(0.9f, h_l[j], fmaf(0.1f, I, 0.01f * nz_l[j]));
      h_l[j] = hn;
    }
    __syncthreads();
  }
  if (t < HID_N) hb[(size_t)(S_N - 1) * HID_N + t] = h_l[t];
}

// ---------------------------------------------------------------- kernel 3
// 256 thr = 4 waves; each wave handles 8 (b,t) pairs. lane = output o.
// sigmoid(hidden[:, :EXC]) staged in LDS; W_ho row per lane from global
// (scalar loads, L1-resident working set). Softmax via 64-lane shfl.
__global__ __launch_bounds__(256) void k_logits(
    const float* __restrict__ hid, const float* __restrict__ W_ho,
    float* __restrict__ out)
{
  __shared__ float s2[4][8][416];    // 53.2 KB
  const int wave = threadIdx.x >> 6, lane = threadIdx.x & 63;
  const int base = (blockIdx.x * 4 + wave) * 8;

  #pragma unroll 1
  for (int p = 0; p < 8; ++p) {
    const float* hr = hid + (size_t)(base + p) * HID_N;
    #pragma unroll
    for (int c = 0; c < 7; ++c) {
      int e = c * 64 + lane;
      if (e < 416) s2[wave][p][e] = (e < EXC_N) ? sigf(hr[e]) : 0.f;
    }
  }
  __syncthreads();

  const float* wr = W_ho + (size_t)lane * EXC_N;
  float acc[8];
  #pragma unroll
  for (int p = 0; p < 8; ++p) acc[p] = 0.f;

  #pragma unroll 1
  for (int c = 0; c < 102; ++c) {    // e = 4c .. 4c+3  (<= 407)
    float w0 = wr[4 * c + 0], w1 = wr[4 * c + 1];
    float w2 = wr[4 * c + 2], w3 = wr[4 * c + 3];
    #pragma unroll
    for (int p = 0; p < 8; ++p) {
      float4 s4 = *(const float4*)&s2[wave][p][4 * c];   // broadcast
      acc[p] = fmaf(w0, s4.x, acc[p]);
      acc[p] = fmaf(w1, s4.y, acc[p]);
      acc[p] = fmaf(w2, s4.z, acc[p]);
      acc[p] = fmaf(w3, s4.w, acc[p]);
    }
  }
  {  // tail e = 408, 409 (keeps W_ho row reads in-bounds for lane 63)
    float w0 = wr[408], w1 = wr[409];
    #pragma unroll
    for (int p = 0; p < 8; ++p) {
      acc[p] = fmaf(w0, s2[wave][p][408], acc[p]);
      acc[p] = fmaf(w1, s2[wave][p][409], acc[p]);
    }
  }

  #pragma unroll 1
  for (int p = 0; p < 8; ++p) {
    float lg = acc[p];
    float m = lg;
    #pragma unroll
    for (int d = 1; d < 64; d <<= 1) m = fmaxf(m, __shfl_xor(m, d));
    float ex = __expf(lg - m);
    float sm = ex;
    #pragma unroll
    for (int d = 1; d < 64; d <<= 1) sm += __shfl_xor(sm, d);
    out[(size_t)(base + p) * OUT_N + lane] = ex / sm;
  }
}

// ----------------------------------------------------------------- launch
extern "C" void kernel_launch(void* const* d_in, const int* in_sizes, int n_in,
                              void* d_out, int out_size, void* d_ws, size_t ws_size,
                              hipStream_t stream) {
  (void)in_sizes; (void)n_in; (void)out_size; (void)d_ws; (void)ws_size;
  const float* x     = (const float*)d_in[0];
  const float* h0    = (const float*)d_in[1];
  const float* W_ih  = (const float*)d_in[2];
  const float* W_hh  = (const float*)d_in[3];
  const float* W_ho  = (const float*)d_in[4];
  const float* noise = (const float*)d_in[5];
  float* out = (float*)d_out;
  float* hid = out + (size_t)PAIRS * OUT_N;   // hidden part of d_out

  k_input <<<PAIRS / (8 * 16), 512, 0, stream>>>(x, W_ih, hid);
  k_scan  <<<B_N, 1024, 0, stream>>>(h0, W_hh, noise, hid);
  k_logits<<<PAIRS / (4 * 8), 256, 0, stream>>>(hid, W_ho, out);
}

// Round 2
// 5610.705 us; speedup vs baseline: 6.6462x; 6.6462x over previous
//
#include <hip/hip_runtime.h>
#include <hip/hip_fp16.h>

// RateRNN with Dale's law — MI355X (gfx950)
//
//  k_input : I_exc = relu(x @ W_ih^T)  -> written into d_out's hidden slots
//  k_scan  : 2048 sequential steps; 32 blocks (1 per batch), 512 threads,
//            one ROW of W_hh per thread, stored f16:
//              - k in [0,384): 192 packed words in VGPRs (launch_bounds(512,2)
//                -> 256-VGPR cap, per-SIMD pool 512 regs, 2 waves/SIMD)
//              - k in [384,512): 64 words/row in LDS, row stride padded to 68
//                words so wave reads spread over all 32 banks (BW-bound only)
//            s = sigmoid(h) distributed by v_readlane (VALU pipe; LDS
//            broadcast of s would cost ~5000 cyc/step on the shared LDS pipe).
//            dot = v_dot2_f32_f16, 4 accumulator chains.
//  k_logits: out = softmax(sigmoid(hidden[:, :, :EXC]) @ W_ho^T)

#define B_N 32
#define S_N 2048
#define IN_N 64
#define OUT_N 64
#define HID_N 512
#define EXC_N 410
#define PAIRS (B_N * S_N)

// dynamic-LDS word offsets for k_scan
#define WL_WORDS (HID_N * 68)        // 34816 words = 139264 B
#define HB0_OFF  WL_WORDS            // 512 floats
#define HB1_OFF  (WL_WORDS + 512)    // 512 floats
#define OSC_OFF  (WL_WORDS + 1024)   // 2048 floats
#define LDS_BYTES ((WL_WORDS + 1024 + S_N) * 4)   // 151552

typedef _Float16 h2_t __attribute__((ext_vector_type(2)));

__device__ __forceinline__ float sigf(float v) {
  return 1.0f / (1.0f + __expf(-v));
}

__device__ __forceinline__ unsigned pack_h2(float a, float b) {
  __half2 hp = __floats2half2_rn(a, b);   // RNE cvt x2 + pack
  return __builtin_bit_cast(unsigned, hp);
}

__device__ __forceinline__ float dot2(unsigned w, unsigned s, float acc) {
  return __builtin_amdgcn_fdot2(__builtin_bit_cast(h2_t, w),
                                __builtin_bit_cast(h2_t, s), acc, false);
}

// ---------------------------------------------------------------- kernel 1
__global__ __launch_bounds__(512) void k_input(
    const float* __restrict__ x, const float* __restrict__ W_ih,
    float* __restrict__ hid)
{
  __shared__ float4 xl[8][16][16];   // 32 KB
  const int wave = threadIdx.x >> 6, lane = threadIdx.x & 63;
  const int base = (blockIdx.x * 8 + wave) * 16;

  const float4* xg = (const float4*)(x + (size_t)base * IN_N);
  #pragma unroll
  for (int it = 0; it < 4; ++it) {
    int k = it * 64 + lane;
    xl[wave][k >> 4][k & 15] = xg[k];
  }
  __syncthreads();

  #pragma unroll 1
  for (int c = 0; c < 7; ++c) {
    int e = c * 64 + lane;
    bool ok = (e < EXC_N);
    float acc[16];
    #pragma unroll
    for (int p = 0; p < 16; ++p) acc[p] = 0.f;
    const float4* wrow = (const float4*)(W_ih + (size_t)(ok ? e : 0) * IN_N);
    #pragma unroll
    for (int i4 = 0; i4 < 16; ++i4) {
      float4 w4 = wrow[i4];
      #pragma unroll
      for (int p = 0; p < 16; ++p) {
        float4 x4 = xl[wave][p][i4];
        acc[p] = fmaf(w4.x, x4.x, acc[p]);
        acc[p] = fmaf(w4.y, x4.y, acc[p]);
        acc[p] = fmaf(w4.z, x4.z, acc[p]);
        acc[p] = fmaf(w4.w, x4.w, acc[p]);
      }
    }
    if (ok) {
      #pragma unroll
      for (int p = 0; p < 16; ++p)
        hid[(size_t)(base + p) * HID_N + e] = fmaxf(acc[p], 0.f);
    }
  }
}

// ---------------------------------------------------------------- kernel 2
__global__ __launch_bounds__(512, 2) void k_scan(
    const float* __restrict__ h0, const float* __restrict__ W_hh,
    const float* __restrict__ noise, float* __restrict__ hid)
{
  extern __shared__ unsigned lds[];
  unsigned* Wl   = lds;
  float*    hb0  = (float*)(lds + HB0_OFF);
  float*    hb1  = (float*)(lds + HB1_OFF);
  float*    oscl = (float*)(lds + OSC_OFF);

  const int t = threadIdx.x;       // row index r = t
  const int b = blockIdx.x;
  const int lane = t & 63;

  // ---- preamble: W row -> f16. k<384 to 192 VGPR words, k>=384 to LDS.
  const float2* wrow = (const float2*)(W_hh + (size_t)t * HID_N);
  unsigned w[192];
  #pragma unroll
  for (int m = 0; m < 192; ++m) {
    float2 p = wrow[m];
    w[m] = pack_h2(p.x, p.y);
  }
  #pragma unroll
  for (int m = 0; m < 64; ++m) {
    float2 p = wrow[192 + m];
    Wl[t * 68 + m] = pack_h2(p.x, p.y);
  }
  // osc table (uniform per step; read only by rows >= EXC_N)
  #pragma unroll
  for (int q = 0; q < S_N / 512; ++q) {
    int st = q * 512 + t;
    oscl[st] = sinf((50.26548245743669f * (float)st) * 0.01f) + 1.0f;
  }

  float hr = h0[(size_t)b * HID_N + t];
  hb0[t] = hr;

  float* hb = hid + (size_t)b * S_N * HID_N;

  // step-0 streams
  float ie_r = 0.f;
  if (t < EXC_N) ie_r = hb[t];
  float nz_r = noise[(size_t)b * HID_N + t];
  __syncthreads();

  #pragma unroll 1
  for (int step = 0; step < S_N; ++step) {
    const float* hcur = (step & 1) ? hb1 : hb0;
    float*       hnxt = (step & 1) ? hb0 : hb1;

    // ---- s-phase: this lane packs s-words {lane, 64+lane, 128+lane, 192+lane}
    unsigned vs[4];
    #pragma unroll
    for (int q = 0; q < 4; ++q) {
      float2 hp = *(const float2*)&hcur[q * 128 + 2 * lane];
      vs[q] = pack_h2(sigf(hp.x), sigf(hp.y));
    }

    // ---- prefetch next-step streams (latency hidden under the dot)
    int ns = (step + 1 < S_N) ? step + 1 : step;
    float ie_n = 0.f, nz_n;
    if (t < EXC_N) ie_n = hb[(size_t)ns * HID_N + t];
    nz_n = noise[((size_t)ns * B_N + b) * HID_N + t];

    // ---- dot: y[t] = sum_k W[t][k] * s[k]
    float a0 = 0.f, a1 = 0.f, a2 = 0.f, a3 = 0.f;
    #pragma unroll
    for (int m = 0; m < 192; m += 4) {
      unsigned s0 = (unsigned)__builtin_amdgcn_readlane((int)vs[m >> 6], (m + 0) & 63);
      unsigned s1 = (unsigned)__builtin_amdgcn_readlane((int)vs[m >> 6], (m + 1) & 63);
      unsigned s2 = (unsigned)__builtin_amdgcn_readlane((int)vs[m >> 6], (m + 2) & 63);
      unsigned s3 = (unsigned)__builtin_amdgcn_readlane((int)vs[m >> 6], (m + 3) & 63);
      a0 = dot2(w[m + 0], s0, a0);
      a1 = dot2(w[m + 1], s1, a1);
      a2 = dot2(w[m + 2], s2, a2);
      a3 = dot2(w[m + 3], s3, a3);
    }
    #pragma unroll
    for (int c = 0; c < 16; ++c) {
      uint4 wd = *(const uint4*)&Wl[t * 68 + 4 * c];     // ds_read_b128, 8-way spread
      unsigned s0 = (unsigned)__builtin_amdgcn_readlane((int)vs[3], 4 * c + 0);
      unsigned s1 = (unsigned)__builtin_amdgcn_readlane((int)vs[3], 4 * c + 1);
      unsigned s2 = (unsigned)__builtin_amdgcn_readlane((int)vs[3], 4 * c + 2);
      unsigned s3 = (unsigned)__builtin_amdgcn_readlane((int)vs[3], 4 * c + 3);
      a0 = dot2(wd.x, s0, a0);
      a1 = dot2(wd.y, s1, a1);
      a2 = dot2(wd.z, s2, a2);
      a3 = dot2(wd.w, s3, a3);
    }
    float y = (a0 + a1) + (a2 + a3);

    // ---- update
    float rlu = fmaxf(y, 0.f);
    float I = (t < EXC_N) ? (rlu + ie_r) : (oscl[step] - rlu);
    float hn = 0.9f * hr + 0.1f * I + 0.01f * nz_r;
    hr = hn;
    hb[(size_t)step * HID_N + t] = hn;   // coalesced 64-wide per wave
    hnxt[t] = hn;
    ie_r = ie_n;
    nz_r = nz_n;
    __syncthreads();
  }
}

// ---------------------------------------------------------------- kernel 3
__global__ __launch_bounds__(256) void k_logits(
    const float* __restrict__ hid, const float* __restrict__ W_ho,
    float* __restrict__ out)
{
  __shared__ float s2[4][8][416];    // 53.2 KB
  const int wave = threadIdx.x >> 6, lane = threadIdx.x & 63;
  const int base = (blockIdx.x * 4 + wave) * 8;

  #pragma unroll 1
  for (int p = 0; p < 8; ++p) {
    const float* hr = hid + (size_t)(base + p) * HID_N;
    #pragma unroll
    for (int c = 0; c < 7; ++c) {
      int e = c * 64 + lane;
      if (e < 416) s2[wave][p][e] = (e < EXC_N) ? sigf(hr[e]) : 0.f;
    }
  }
  __syncthreads();

  const float* wr = W_ho + (size_t)lane * EXC_N;
  float acc[8];
  #pragma unroll
  for (int p = 0; p < 8; ++p) acc[p] = 0.f;

  #pragma unroll 1
  for (int c = 0; c < 102; ++c) {
    float w0 = wr[4 * c + 0], w1 = wr[4 * c + 1];
    float w2 = wr[4 * c + 2], w3 = wr[4 * c + 3];
    #pragma unroll
    for (int p = 0; p < 8; ++p) {
      float4 s4 = *(const float4*)&s2[wave][p][4 * c];
      acc[p] = fmaf(w0, s4.x, acc[p]);
      acc[p] = fmaf(w1, s4.y, acc[p]);
      acc[p] = fmaf(w2, s4.z, acc[p]);
      acc[p] = fmaf(w3, s4.w, acc[p]);
    }
  }
  {
    float w0 = wr[408], w1 = wr[409];
    #pragma unroll
    for (int p = 0; p < 8; ++p) {
      acc[p] = fmaf(w0, s2[wave][p][408], acc[p]);
      acc[p] = fmaf(w1, s2[wave][p][409], acc[p]);
    }
  }

  #pragma unroll 1
  for (int p = 0; p < 8; ++p) {
    float lg = acc[p];
    float m = lg;
    #pragma unroll
    for (int d = 1; d < 64; d <<= 1) m = fmaxf(m, __shfl_xor(m, d));
    float ex = __expf(lg - m);
    float sm = ex;
    #pragma unroll
    for (int d = 1; d < 64; d <<= 1) sm += __shfl_xor(sm, d);
    out[(size_t)(base + p) * OUT_N + lane] = ex / sm;
  }
}

// ----------------------------------------------------------------- launch
extern "C" void kernel_launch(void* const* d_in, const int* in_sizes, int n_in,
                              void* d_out, int out_size, void* d_ws, size_t ws_size,
                              hipStream_t stream) {
  (void)in_sizes; (void)n_in; (void)out_size; (void)d_ws; (void)ws_size;
  const float* x     = (const float*)d_in[0];
  const float* h0    = (const float*)d_in[1];
  const float* W_ih  = (const float*)d_in[2];
  const float* W_hh  = (const float*)d_in[3];
  const float* W_ho  = (const float*)d_in[4];
  const float* noise = (const float*)d_in[5];
  float* out = (float*)d_out;
  float* hid = out + (size_t)PAIRS * OUT_N;

  hipFuncSetAttribute(reinterpret_cast<const void*>(&k_scan),
                      hipFuncAttributeMaxDynamicSharedMemorySize, LDS_BYTES);

  k_input <<<PAIRS / (8 * 16), 512, 0, stream>>>(x, W_ih, hid);
  k_scan  <<<B_N, 512, LDS_BYTES, stream>>>(h0, W_hh, noise, hid);
  k_logits<<<PAIRS / (4 * 8), 256, 0, stream>>>(hid, W_ho, out);
}

// Round 9
// 4190.392 us; speedup vs baseline: 8.8989x; 1.3389x over previous
//
#include <hip/hip_runtime.h>
#include <hip/hip_fp16.h>

// RateRNN with Dale's law — MI355X (gfx950)
//
//  k_scan v3: 32 blocks (1 CU/batch), 512 thr. Thread owns 4 rows x 128 k
//  of W_hh (f16). kg = wave&3 (wave-uniform k-slice), jhalf = wave>>2.
//    rows r=0..2 : 192 packed f16x2 words in VGPRs, pinned live by empty
//                  asm ("+v") each step (defeats the remat-to-L2 that made
//                  round-2 run at VGPR_Count=128).
//    row  r=3    : LDS, transposed [c][thread] so the per-step 64 x
//                  ds_read_b32 are conflict-free (lane-consecutive).
//    s-slice     : wave-uniform -> 16 x ds_read_b128 broadcast, reused
//                  across the 4 rows (replaces 256 readlanes of round 2).
//  Per-step: [A: dot -> LDS partials] bar [B: 4-way reduce, h-update,
//  s-pack f16 -> LDS, coalesced h store] bar.   2 barriers/step.

#define B_N 32
#define S_N 2048
#define IN_N 64
#define OUT_N 64
#define HID_N 512
#define EXC_N 410
#define PAIRS (B_N * S_N)

// dynamic-LDS word offsets for k_scan
#define WL3_WORDS (64 * 512)            // 32768 words = 128 KB  [c][t]
#define S_OFF     WL3_WORDS             // 256 words  (512 f16)
#define PART_OFF  (S_OFF + 256)         // 2048 words (part[kg][row] f32)
#define OSC_OFF   (PART_OFF + 2048)     // 2048 words f32
#define LDS_WORDS (OSC_OFF + 2048)      // 37120
#define LDS_BYTES (LDS_WORDS * 4)       // 148480

typedef _Float16 h2_t __attribute__((ext_vector_type(2)));
typedef unsigned u32x4 __attribute__((ext_vector_type(4)));

__device__ __forceinline__ float sigf(float v) {
  return 1.0f / (1.0f + __expf(-v));
}
__device__ __forceinline__ unsigned pack_h2(float a, float b) {
  __half2 hp = __floats2half2_rn(a, b);
  return __builtin_bit_cast(unsigned, hp);
}
__device__ __forceinline__ float dot2(unsigned w, unsigned s, float acc) {
  return __builtin_amdgcn_fdot2(__builtin_bit_cast(h2_t, w),
                                __builtin_bit_cast(h2_t, s), acc, false);
}

// ---------------------------------------------------------------- kernel 1
__global__ __launch_bounds__(512) void k_input(
    const float* __restrict__ x, const float* __restrict__ W_ih,
    float* __restrict__ hid)
{
  __shared__ float4 xl[8][16][16];   // 32 KB
  const int wave = threadIdx.x >> 6, lane = threadIdx.x & 63;
  const int base = (blockIdx.x * 8 + wave) * 16;

  const float4* xg = (const float4*)(x + (size_t)base * IN_N);
  #pragma unroll
  for (int it = 0; it < 4; ++it) {
    int k = it * 64 + lane;
    xl[wave][k >> 4][k & 15] = xg[k];
  }
  __syncthreads();

  #pragma unroll 1
  for (int c = 0; c < 7; ++c) {
    int e = c * 64 + lane;
    bool ok = (e < EXC_N);
    float acc[16];
    #pragma unroll
    for (int p = 0; p < 16; ++p) acc[p] = 0.f;
    const float4* wrow = (const float4*)(W_ih + (size_t)(ok ? e : 0) * IN_N);
    #pragma unroll
    for (int i4 = 0; i4 < 16; ++i4) {
      float4 w4 = wrow[i4];
      #pragma unroll
      for (int p = 0; p < 16; ++p) {
        float4 x4 = xl[wave][p][i4];
        acc[p] = fmaf(w4.x, x4.x, acc[p]);
        acc[p] = fmaf(w4.y, x4.y, acc[p]);
        acc[p] = fmaf(w4.z, x4.z, acc[p]);
        acc[p] = fmaf(w4.w, x4.w, acc[p]);
      }
    }
    if (ok) {
      #pragma unroll
      for (int p = 0; p < 16; ++p)
        hid[(size_t)(base + p) * HID_N + e] = fmaxf(acc[p], 0.f);
    }
  }
}

// ---------------------------------------------------------------- kernel 2
__global__ __launch_bounds__(512, 2) void k_scan(
    const float* __restrict__ h0, const float* __restrict__ W_hh,
    const float* __restrict__ noise, float* __restrict__ hid)
{
  extern __shared__ unsigned lds[];
  float* ldsf = (float*)lds;

  const int t = threadIdx.x;
  const int b = blockIdx.x;
  const int wave = t >> 6, lane = t & 63;
  const int kg = wave & 3;          // k-slice  [kg*128, kg*128+128) halves
  const int jh = wave >> 2;         // row group base jh*256
  const int row0 = jh * 256 + lane * 4;   // rows row0..row0+3

  // ---- preamble: W -> f16. rows 0..2 to 192 VGPR words, row 3 to LDS.
  unsigned w[192];
  #pragma unroll
  for (int r = 0; r < 3; ++r) {
    const float2* wr = (const float2*)(W_hh + (size_t)(row0 + r) * HID_N + kg * 128);
    #pragma unroll
    for (int m = 0; m < 64; ++m) {
      float2 p = wr[m];
      w[r * 64 + m] = pack_h2(p.x, p.y);
    }
  }
  {
    const float2* wr = (const float2*)(W_hh + (size_t)(row0 + 3) * HID_N + kg * 128);
    #pragma unroll
    for (int m = 0; m < 64; ++m) {
      float2 p = wr[m];
      lds[m * 512 + t] = pack_h2(p.x, p.y);     // transposed [c][t]
    }
  }
  // osc table
  #pragma unroll
  for (int q = 0; q < S_N / 512; ++q) {
    int st = q * 512 + t;
    ldsf[OSC_OFF + st] = sinf((50.26548245743669f * (float)st) * 0.01f) + 1.0f;
  }

  // h, s0
  float h = h0[(size_t)b * HID_N + t];
  {
    __half* sp = (__half*)((char*)lds + S_OFF * 4);
    sp[t] = __float2half_rn(sigf(h));
  }

  float* hb = hid + (size_t)b * S_N * HID_N;

  float ie_r = 0.f;
  if (t < EXC_N) ie_r = hb[t];
  float nz_r = noise[(size_t)b * HID_N + t];
  __syncthreads();

  const u32x4* sbase = (const u32x4*)(lds + S_OFF) + kg * 16;   // wave-uniform

  #pragma unroll 1
  for (int step = 0; step < S_N; ++step) {
    // pin W words live in VGPRs (no instr emitted; defeats remat/reload)
    #pragma unroll
    for (int i = 0; i < 192; ++i) asm volatile("" : "+v"(w[i]));

    // ---- phase A: dot over own k-slice, 4 rows ----
    float aA0 = 0.f, aB0 = 0.f, aA1 = 0.f, aB1 = 0.f;
    float aA2 = 0.f, aB2 = 0.f, aA3 = 0.f, aB3 = 0.f;
    #pragma unroll
    for (int c4 = 0; c4 < 16; ++c4) {
      u32x4 s4 = sbase[c4];                    // ds_read_b128 broadcast
      unsigned w3_0 = lds[(4 * c4 + 0) * 512 + t];
      unsigned w3_1 = lds[(4 * c4 + 1) * 512 + t];
      unsigned w3_2 = lds[(4 * c4 + 2) * 512 + t];
      unsigned w3_3 = lds[(4 * c4 + 3) * 512 + t];
      aA0 = dot2(w[      4 * c4 + 0], s4[0], aA0);
      aA1 = dot2(w[ 64 + 4 * c4 + 0], s4[0], aA1);
      aA2 = dot2(w[128 + 4 * c4 + 0], s4[0], aA2);
      aA3 = dot2(w3_0,                s4[0], aA3);
      aB0 = dot2(w[      4 * c4 + 1], s4[1], aB0);
      aB1 = dot2(w[ 64 + 4 * c4 + 1], s4[1], aB1);
      aB2 = dot2(w[128 + 4 * c4 + 1], s4[1], aB2);
      aB3 = dot2(w3_1,                s4[1], aB3);
      aA0 = dot2(w[      4 * c4 + 2], s4[2], aA0);
      aA1 = dot2(w[ 64 + 4 * c4 + 2], s4[2], aA1);
      aA2 = dot2(w[128 + 4 * c4 + 2], s4[2], aA2);
      aA3 = dot2(w3_2,                s4[2], aA3);
      aB0 = dot2(w[      4 * c4 + 3], s4[3], aB0);
      aB1 = dot2(w[ 64 + 4 * c4 + 3], s4[3], aB1);
      aB2 = dot2(w[128 + 4 * c4 + 3], s4[3], aB2);
      aB3 = dot2(w3_3,                s4[3], aB3);
    }
    // partials: part[kg][row0..row0+3]
    {
      float4 pv = make_float4(aA0 + aB0, aA1 + aB1, aA2 + aB2, aA3 + aB3);
      *(float4*)(ldsf + PART_OFF + kg * 512 + row0) = pv;
    }

    // ---- prefetch next-step streams (consumed at end of phase B) ----
    int ns = (step + 1 < S_N) ? step + 1 : step;
    float ie_n = 0.f, nz_n;
    if (t < EXC_N) ie_n = hb[(size_t)ns * HID_N + t];
    nz_n = noise[((size_t)ns * B_N + b) * HID_N + t];
    __syncthreads();

    // ---- phase B: reduce 4 partials, update own row t ----
    float y = (ldsf[PART_OFF + t]        + ldsf[PART_OFF + 512 + t]) +
              (ldsf[PART_OFF + 1024 + t] + ldsf[PART_OFF + 1536 + t]);
    float rlu = fmaxf(y, 0.f);
    float osc = ldsf[OSC_OFF + step];                 // uniform broadcast
    float I = (t < EXC_N) ? (rlu + ie_r) : (osc - rlu);
    float hn = 0.9f * h + 0.1f * I + 0.01f * nz_r;
    h = hn;
    hb[(size_t)step * HID_N + t] = hn;                // coalesced
    {
      __half* sp = (__half*)((char*)lds + S_OFF * 4);
      sp[t] = __float2half_rn(sigf(hn));
    }
    ie_r = ie_n;
    nz_r = nz_n;
    __syncthreads();
  }
}

// ---------------------------------------------------------------- kernel 3
__global__ __launch_bounds__(256) void k_logits(
    const float* __restrict__ hid, const float* __restrict__ W_ho,
    float* __restrict__ out)
{
  __shared__ float s2[4][8][416];    // 53.2 KB
  const int wave = threadIdx.x >> 6, lane = threadIdx.x & 63;
  const int base = (blockIdx.x * 4 + wave) * 8;

  #pragma unroll 1
  for (int p = 0; p < 8; ++p) {
    const float* hr = hid + (size_t)(base + p) * HID_N;
    #pragma unroll
    for (int c = 0; c < 7; ++c) {
      int e = c * 64 + lane;
      if (e < 416) s2[wave][p][e] = (e < EXC_N) ? sigf(hr[e]) : 0.f;
    }
  }
  __syncthreads();

  const float* wr = W_ho + (size_t)lane * EXC_N;
  float acc[8];
  #pragma unroll
  for (int p = 0; p < 8; ++p) acc[p] = 0.f;

  #pragma unroll 1
  for (int c = 0; c < 102; ++c) {
    float w0 = wr[4 * c + 0], w1 = wr[4 * c + 1];
    float w2 = wr[4 * c + 2], w3 = wr[4 * c + 3];
    #pragma unroll
    for (int p = 0; p < 8; ++p) {
      float4 s4 = *(const float4*)&s2[wave][p][4 * c];
      acc[p] = fmaf(w0, s4.x, acc[p]);
      acc[p] = fmaf(w1, s4.y, acc[p]);
      acc[p] = fmaf(w2, s4.z, acc[p]);
      acc[p] = fmaf(w3, s4.w, acc[p]);
    }
  }
  {
    float w0 = wr[408], w1 = wr[409];
    #pragma unroll
    for (int p = 0; p < 8; ++p) {
      acc[p] = fmaf(w0, s2[wave][p][408], acc[p]);
      acc[p] = fmaf(w1, s2[wave][p][409], acc[p]);
    }
  }

  #pragma unroll 1
  for (int p = 0; p < 8; ++p) {
    float lg = acc[p];
    float m = lg;
    #pragma unroll
    for (int d = 1; d < 64; d <<= 1) m = fmaxf(m, __shfl_xor(m, d));
    float ex = __expf(lg - m);
    float sm = ex;
    #pragma unroll
    for (int d = 1; d < 64; d <<= 1) sm += __shfl_xor(sm, d);
    out[(size_t)(base + p) * OUT_N + lane] = ex / sm;
  }
}

// ----------------------------------------------------------------- launch
extern "C" void kernel_launch(void* const* d_in, const int* in_sizes, int n_in,
                              void* d_out, int out_size, void* d_ws, size_t ws_size,
                              hipStream_t stream) {
  (void)in_sizes; (void)n_in; (void)out_size; (void)d_ws; (void)ws_size;
  const float* x     = (const float*)d_in[0];
  const float* h0    = (const float*)d_in[1];
  const float* W_ih  = (const float*)d_in[2];
  const float* W_hh  = (const float*)d_in[3];
  const float* W_ho  = (const float*)d_in[4];
  const float* noise = (const float*)d_in[5];
  float* out = (float*)d_out;
  float* hid = out + (size_t)PAIRS * OUT_N;

  hipFuncSetAttribute(reinterpret_cast<const void*>(&k_scan),
                      hipFuncAttributeMaxDynamicSharedMemorySize, LDS_BYTES);

  k_input <<<PAIRS / (8 * 16), 512, 0, stream>>>(x, W_ih, hid);
  k_scan  <<<B_N, 512, LDS_BYTES, stream>>>(h0, W_hh, noise, hid);
  k_logits<<<PAIRS / (4 * 8), 256, 0, stream>>>(hid, W_ho, out);
}

// Round 10
// 4188.619 us; speedup vs baseline: 8.9026x; 1.0004x over previous
//
#include <hip/hip_runtime.h>
#include <hip/hip_fp16.h>

// RateRNN with Dale's law — MI355X (gfx950)
//
//  k_scan v4 = v3 + amdgpu_waves_per_eu(2,2).
//  Round-9 evidence: VGPR_Count=128 persisted with asm pins -> allocator's
//  occupancy target (4 waves/EU, it can't see the 148KB dynamic LDS cap)
//  kept w[] homed in AGPR/scratch, adding ~300 VALU instrs/thread/step
//  (local VALUBusy 55%, 4440 cyc/step vs ~1500 model). waves_per_eu(2,2)
//  pins the target at 2 waves/EU -> 256-VGPR budget -> w[] in arch VGPRs.
//
//  Structure (unchanged from v3): 32 blocks (1 CU/batch), 512 thr.
//  Thread owns 4 rows x 128 k of W_hh (f16): rows 0-2 in 192 VGPR words
//  (asm-pinned live each step), row 3 in LDS transposed [c][t] (conflict-
//  free, verified: SQ_LDS_BANK_CONFLICT=0). s-slice wave-uniform ->
//  16x ds_read_b128 broadcast reused across 4 rows. 2 barriers/step.

#define B_N 32
#define S_N 2048
#define IN_N 64
#define OUT_N 64
#define HID_N 512
#define EXC_N 410
#define PAIRS (B_N * S_N)

// dynamic-LDS word offsets for k_scan
#define WL3_WORDS (64 * 512)            // 32768 words = 128 KB  [c][t]
#define S_OFF     WL3_WORDS             // 256 words  (512 f16)
#define PART_OFF  (S_OFF + 256)         // 2048 words (part[kg][row] f32)
#define OSC_OFF   (PART_OFF + 2048)     // 2048 words f32
#define LDS_WORDS (OSC_OFF + 2048)      // 37120
#define LDS_BYTES (LDS_WORDS * 4)       // 148480

typedef _Float16 h2_t __attribute__((ext_vector_type(2)));
typedef unsigned u32x4 __attribute__((ext_vector_type(4)));

__device__ __forceinline__ float sigf(float v) {
  return 1.0f / (1.0f + __expf(-v));
}
__device__ __forceinline__ unsigned pack_h2(float a, float b) {
  __half2 hp = __floats2half2_rn(a, b);
  return __builtin_bit_cast(unsigned, hp);
}
__device__ __forceinline__ float dot2(unsigned w, unsigned s, float acc) {
  return __builtin_amdgcn_fdot2(__builtin_bit_cast(h2_t, w),
                                __builtin_bit_cast(h2_t, s), acc, false);
}

// ---------------------------------------------------------------- kernel 1
__global__ __launch_bounds__(512) void k_input(
    const float* __restrict__ x, const float* __restrict__ W_ih,
    float* __restrict__ hid)
{
  __shared__ float4 xl[8][16][16];   // 32 KB
  const int wave = threadIdx.x >> 6, lane = threadIdx.x & 63;
  const int base = (blockIdx.x * 8 + wave) * 16;

  const float4* xg = (const float4*)(x + (size_t)base * IN_N);
  #pragma unroll
  for (int it = 0; it < 4; ++it) {
    int k = it * 64 + lane;
    xl[wave][k >> 4][k & 15] = xg[k];
  }
  __syncthreads();

  #pragma unroll 1
  for (int c = 0; c < 7; ++c) {
    int e = c * 64 + lane;
    bool ok = (e < EXC_N);
    float acc[16];
    #pragma unroll
    for (int p = 0; p < 16; ++p) acc[p] = 0.f;
    const float4* wrow = (const float4*)(W_ih + (size_t)(ok ? e : 0) * IN_N);
    #pragma unroll
    for (int i4 = 0; i4 < 16; ++i4) {
      float4 w4 = wrow[i4];
      #pragma unroll
      for (int p = 0; p < 16; ++p) {
        float4 x4 = xl[wave][p][i4];
        acc[p] = fmaf(w4.x, x4.x, acc[p]);
        acc[p] = fmaf(w4.y, x4.y, acc[p]);
        acc[p] = fmaf(w4.z, x4.z, acc[p]);
        acc[p] = fmaf(w4.w, x4.w, acc[p]);
      }
    }
    if (ok) {
      #pragma unroll
      for (int p = 0; p < 16; ++p)
        hid[(size_t)(base + p) * HID_N + e] = fmaxf(acc[p], 0.f);
    }
  }
}

// ---------------------------------------------------------------- kernel 2
__global__ __attribute__((amdgpu_waves_per_eu(2, 2)))
__launch_bounds__(512) void k_scan(
    const float* __restrict__ h0, const float* __restrict__ W_hh,
    const float* __restrict__ noise, float* __restrict__ hid)
{
  extern __shared__ unsigned lds[];
  float* ldsf = (float*)lds;

  const int t = threadIdx.x;
  const int b = blockIdx.x;
  const int wave = t >> 6, lane = t & 63;
  const int kg = wave & 3;          // k-slice  [kg*128, kg*128+128) halves
  const int jh = wave >> 2;         // row group base jh*256
  const int row0 = jh * 256 + lane * 4;   // rows row0..row0+3

  // ---- preamble: W -> f16. rows 0..2 to 192 VGPR words, row 3 to LDS.
  unsigned w[192];
  #pragma unroll
  for (int r = 0; r < 3; ++r) {
    const float2* wr = (const float2*)(W_hh + (size_t)(row0 + r) * HID_N + kg * 128);
    #pragma unroll
    for (int m = 0; m < 64; ++m) {
      float2 p = wr[m];
      w[r * 64 + m] = pack_h2(p.x, p.y);
    }
  }
  {
    const float2* wr = (const float2*)(W_hh + (size_t)(row0 + 3) * HID_N + kg * 128);
    #pragma unroll
    for (int m = 0; m < 64; ++m) {
      float2 p = wr[m];
      lds[m * 512 + t] = pack_h2(p.x, p.y);     // transposed [c][t]
    }
  }
  // osc table
  #pragma unroll
  for (int q = 0; q < S_N / 512; ++q) {
    int st = q * 512 + t;
    ldsf[OSC_OFF + st] = sinf((50.26548245743669f * (float)st) * 0.01f) + 1.0f;
  }

  // h, s0
  float h = h0[(size_t)b * HID_N + t];
  {
    __half* sp = (__half*)((char*)lds + S_OFF * 4);
    sp[t] = __float2half_rn(sigf(h));
  }

  float* hb = hid + (size_t)b * S_N * HID_N;

  float ie_r = 0.f;
  if (t < EXC_N) ie_r = hb[t];
  float nz_r = noise[(size_t)b * HID_N + t];
  __syncthreads();

  const u32x4* sbase = (const u32x4*)(lds + S_OFF) + kg * 16;   // wave-uniform

  #pragma unroll 1
  for (int step = 0; step < S_N; ++step) {
    // pin W words live in VGPRs (no instr emitted; defeats remat/reload)
    #pragma unroll
    for (int i = 0; i < 192; ++i) asm volatile("" : "+v"(w[i]));

    // ---- phase A: dot over own k-slice, 4 rows ----
    float aA0 = 0.f, aB0 = 0.f, aA1 = 0.f, aB1 = 0.f;
    float aA2 = 0.f, aB2 = 0.f, aA3 = 0.f, aB3 = 0.f;
    #pragma unroll
    for (int c4 = 0; c4 < 16; ++c4) {
      u32x4 s4 = sbase[c4];                    // ds_read_b128 broadcast
      unsigned w3_0 = lds[(4 * c4 + 0) * 512 + t];
      unsigned w3_1 = lds[(4 * c4 + 1) * 512 + t];
      unsigned w3_2 = lds[(4 * c4 + 2) * 512 + t];
      unsigned w3_3 = lds[(4 * c4 + 3) * 512 + t];
      aA0 = dot2(w[      4 * c4 + 0], s4[0], aA0);
      aA1 = dot2(w[ 64 + 4 * c4 + 0], s4[0], aA1);
      aA2 = dot2(w[128 + 4 * c4 + 0], s4[0], aA2);
      aA3 = dot2(w3_0,                s4[0], aA3);
      aB0 = dot2(w[      4 * c4 + 1], s4[1], aB0);
      aB1 = dot2(w[ 64 + 4 * c4 + 1], s4[1], aB1);
      aB2 = dot2(w[128 + 4 * c4 + 1], s4[1], aB2);
      aB3 = dot2(w3_1,                s4[1], aB3);
      aA0 = dot2(w[      4 * c4 + 2], s4[2], aA0);
      aA1 = dot2(w[ 64 + 4 * c4 + 2], s4[2], aA1);
      aA2 = dot2(w[128 + 4 * c4 + 2], s4[2], aA2);
      aA3 = dot2(w3_2,                s4[2], aA3);
      aB0 = dot2(w[      4 * c4 + 3], s4[3], aB0);
      aB1 = dot2(w[ 64 + 4 * c4 + 3], s4[3], aB1);
      aB2 = dot2(w[128 + 4 * c4 + 3], s4[3], aB2);
      aB3 = dot2(w3_3,                s4[3], aB3);
    }
    // partials: part[kg][row0..row0+3]
    {
      float4 pv = make_float4(aA0 + aB0, aA1 + aB1, aA2 + aB2, aA3 + aB3);
      *(float4*)(ldsf + PART_OFF + kg * 512 + row0) = pv;
    }

    // ---- prefetch next-step streams (consumed at end of phase B) ----
    int ns = (step + 1 < S_N) ? step + 1 : step;
    float ie_n = 0.f, nz_n;
    if (t < EXC_N) ie_n = hb[(size_t)ns * HID_N + t];
    nz_n = noise[((size_t)ns * B_N + b) * HID_N + t];
    __syncthreads();

    // ---- phase B: reduce 4 partials, update own row t ----
    float y = (ldsf[PART_OFF + t]        + ldsf[PART_OFF + 512 + t]) +
              (ldsf[PART_OFF + 1024 + t] + ldsf[PART_OFF + 1536 + t]);
    float rlu = fmaxf(y, 0.f);
    float osc = ldsf[OSC_OFF + step];                 // uniform broadcast
    float I = (t < EXC_N) ? (rlu + ie_r) : (osc - rlu);
    float hn = 0.9f * h + 0.1f * I + 0.01f * nz_r;
    h = hn;
    hb[(size_t)step * HID_N + t] = hn;                // coalesced
    {
      __half* sp = (__half*)((char*)lds + S_OFF * 4);
      sp[t] = __float2half_rn(sigf(hn));
    }
    ie_r = ie_n;
    nz_r = nz_n;
    __syncthreads();
  }
}

// ---------------------------------------------------------------- kernel 3
__global__ __launch_bounds__(256) void k_logits(
    const float* __restrict__ hid, const float* __restrict__ W_ho,
    float* __restrict__ out)
{
  __shared__ float s2[4][8][416];    // 53.2 KB
  const int wave = threadIdx.x >> 6, lane = threadIdx.x & 63;
  const int base = (blockIdx.x * 4 + wave) * 8;

  #pragma unroll 1
  for (int p = 0; p < 8; ++p) {
    const float* hr = hid + (size_t)(base + p) * HID_N;
    #pragma unroll
    for (int c = 0; c < 7; ++c) {
      int e = c * 64 + lane;
      if (e < 416) s2[wave][p][e] = (e < EXC_N) ? sigf(hr[e]) : 0.f;
    }
  }
  __syncthreads();

  const float* wr = W_ho + (size_t)lane * EXC_N;
  float acc[8];
  #pragma unroll
  for (int p = 0; p < 8; ++p) acc[p] = 0.f;

  #pragma unroll 1
  for (int c = 0; c < 102; ++c) {
    float w0 = wr[4 * c + 0], w1 = wr[4 * c + 1];
    float w2 = wr[4 * c + 2], w3 = wr[4 * c + 3];
    #pragma unroll
    for (int p = 0; p < 8; ++p) {
      float4 s4 = *(const float4*)&s2[wave][p][4 * c];
      acc[p] = fmaf(w0, s4.x, acc[p]);
      acc[p] = fmaf(w1, s4.y, acc[p]);
      acc[p] = fmaf(w2, s4.z, acc[p]);
      acc[p] = fmaf(w3, s4.w, acc[p]);
    }
  }
  {
    float w0 = wr[408], w1 = wr[409];
    #pragma unroll
    for (int p = 0; p < 8; ++p) {
      acc[p] = fmaf(w0, s2[wave][p][408], acc[p]);
      acc[p] = fmaf(w1, s2[wave][p][409], acc[p]);
    }
  }

  #pragma unroll 1
  for (int p = 0; p < 8; ++p) {
    float lg = acc[p];
    float m = lg;
    #pragma unroll
    for (int d = 1; d < 64; d <<= 1) m = fmaxf(m, __shfl_xor(m, d));
    float ex = __expf(lg - m);
    float sm = ex;
    #pragma unroll
    for (int d = 1; d < 64; d <<= 1) sm += __shfl_xor(sm, d);
    out[(size_t)(base + p) * OUT_N + lane] = ex / sm;
  }
}

// ----------------------------------------------------------------- launch
extern "C" void kernel_launch(void* const* d_in, const int* in_sizes, int n_in,
                              void* d_out, int out_size, void* d_ws, size_t ws_size,
                              hipStream_t stream) {
  (void)in_sizes; (void)n_in; (void)out_size; (void)d_ws; (void)ws_size;
  const float* x     = (const float*)d_in[0];
  const float* h0    = (const float*)d_in[1];
  const float* W_ih  = (const float*)d_in[2];
  const float* W_hh  = (const float*)d_in[3];
  const float* W_ho  = (const float*)d_in[4];
  const float* noise = (const float*)d_in[5];
  float* out = (float*)d_out;
  float* hid = out + (size_t)PAIRS * OUT_N;

  hipFuncSetAttribute(reinterpret_cast<const void*>(&k_scan),
                      hipFuncAttributeMaxDynamicSharedMemorySize, LDS_BYTES);

  k_input <<<PAIRS / (8 * 16), 512, 0, stream>>>(x, W_ih, hid);
  k_scan  <<<B_N, 512, LDS_BYTES, stream>>>(h0, W_hh, noise, hid);
  k_logits<<<PAIRS / (4 * 8), 256, 0, stream>>>(hid, W_ho, out);
}